// Round 7
// baseline (292.648 us; speedup 1.0000x reference)
//
#include <hip/hip_runtime.h>
#include <math.h>

#define DMODEL 256
#define NH 8
#define DH 32
#define NEG_INF -1e30f

// ======================================================================
// Chunked double-buffered GEMM: 128 thr, tile 32x64, K in chunks of 64.
// (verified round-6 bodies)
// ======================================================================
__device__ __forceinline__ void gemm_chunk(const float (*__restrict__ As)[36],
                                           const float (*__restrict__ Bs)[64],
                                           float acc[4][4])
{
  int tid = threadIdx.x;
  int tx = tid & 15, ty = tid >> 4;
#pragma unroll 8
  for (int k = 0; k < 64; ++k) {
    float4 a  = *(const float4*)&As[k][ty * 4];
    float4 bv = *(const float4*)&Bs[k][tx * 4];
    acc[0][0] = fmaf(a.x, bv.x, acc[0][0]); acc[0][1] = fmaf(a.x, bv.y, acc[0][1]);
    acc[0][2] = fmaf(a.x, bv.z, acc[0][2]); acc[0][3] = fmaf(a.x, bv.w, acc[0][3]);
    acc[1][0] = fmaf(a.y, bv.x, acc[1][0]); acc[1][1] = fmaf(a.y, bv.y, acc[1][1]);
    acc[1][2] = fmaf(a.y, bv.z, acc[1][2]); acc[1][3] = fmaf(a.y, bv.w, acc[1][3]);
    acc[2][0] = fmaf(a.z, bv.x, acc[2][0]); acc[2][1] = fmaf(a.z, bv.y, acc[2][1]);
    acc[2][2] = fmaf(a.z, bv.z, acc[2][2]); acc[2][3] = fmaf(a.z, bv.w, acc[2][3]);
    acc[3][0] = fmaf(a.w, bv.x, acc[3][0]); acc[3][1] = fmaf(a.w, bv.y, acc[3][1]);
    acc[3][2] = fmaf(a.w, bv.z, acc[3][2]); acc[3][3] = fmaf(a.w, bv.w, acc[3][3]);
  }
}

// A supplied by LayerNorm over a 256-wide row held in registers.
__device__ __forceinline__ void gemm_ln(
    const float* __restrict__ Xsrc,
    const float* __restrict__ g, const float* __restrict__ b,
    const float* __restrict__ Bw, int ldb, int m0, int n0,
    float (*__restrict__ As)[64][36], float (*__restrict__ Bs)[64][64],
    float acc[4][4])
{
  int tid = threadIdx.x;
  int r = tid >> 2, p = tid & 3;
  const float* row = Xsrc + (size_t)(m0 + r) * DMODEL;
  float4 v[16];
  float s = 0.f, ss = 0.f;
#pragma unroll
  for (int j = 0; j < 16; ++j) {
    int kg = (j >> 2) * 64 + p * 16 + (j & 3) * 4;
    v[j] = *(const float4*)(row + kg);
    s  += v[j].x + v[j].y + v[j].z + v[j].w;
    ss += v[j].x * v[j].x + v[j].y * v[j].y + v[j].z * v[j].z + v[j].w * v[j].w;
  }
  s  += __shfl_xor(s, 1);  s  += __shfl_xor(s, 2);
  ss += __shfl_xor(ss, 1); ss += __shfl_xor(ss, 2);
  float mean = s * (1.0f / 256.0f);
  float var  = ss * (1.0f / 256.0f) - mean * mean;
  float rstd = rsqrtf(var + 1e-5f);
#pragma unroll
  for (int j = 0; j < 16; ++j) {
    v[j].x = (v[j].x - mean) * rstd;
    v[j].y = (v[j].y - mean) * rstd;
    v[j].z = (v[j].z - mean) * rstd;
    v[j].w = (v[j].w - mean) * rstd;
  }
#pragma unroll
  for (int i = 0; i < 8; ++i) {
    int idx = tid + 128 * i;
    int k = idx >> 4, c = (idx & 15) << 2;
    *(float4*)&Bs[0][k][c] = *(const float4*)(Bw + (size_t)k * ldb + n0 + c);
  }
#pragma unroll
  for (int j = 0; j < 4; ++j) {
    int kl = p * 16 + j * 4;
    float4 gg = *(const float4*)(g + kl);
    float4 bb = *(const float4*)(b + kl);
    As[0][kl + 0][r] = v[j].x * gg.x + bb.x;
    As[0][kl + 1][r] = v[j].y * gg.y + bb.y;
    As[0][kl + 2][r] = v[j].z * gg.z + bb.z;
    As[0][kl + 3][r] = v[j].w * gg.w + bb.w;
  }
  __syncthreads();
  for (int c = 0; c < 4; ++c) {
    int cur = c & 1;
    float4 breg[8];
    if (c < 3) {
      int kb = (c + 1) * 64;
#pragma unroll
      for (int i = 0; i < 8; ++i) {
        int idx = tid + 128 * i;
        int k = idx >> 4, cc = (idx & 15) << 2;
        breg[i] = *(const float4*)(Bw + (size_t)(kb + k) * ldb + n0 + cc);
      }
    }
    gemm_chunk(As[cur], Bs[cur], acc);
    if (c < 3) {
      int nxt = cur ^ 1;
      int kb = (c + 1) * 64;
#pragma unroll
      for (int i = 0; i < 8; ++i) {
        int idx = tid + 128 * i;
        int k = idx >> 4, cc = (idx & 15) << 2;
        *(float4*)&Bs[nxt][k][cc] = breg[i];
      }
#pragma unroll
      for (int j = 0; j < 4; ++j) {
        int kl = p * 16 + j * 4;
        float4 gg = *(const float4*)(g + kb + kl);
        float4 bb = *(const float4*)(b + kb + kl);
        float4 vv = v[(c + 1) * 4 + j];
        As[nxt][kl + 0][r] = vv.x * gg.x + bb.x;
        As[nxt][kl + 1][r] = vv.y * gg.y + bb.y;
        As[nxt][kl + 2][r] = vv.z * gg.z + bb.z;
        As[nxt][kl + 3][r] = vv.w * gg.w + bb.w;
      }
      __syncthreads();
    }
  }
}

// A loaded straight from global (no LN).
__device__ __forceinline__ void gemm_copy(
    const float* __restrict__ A, int lda, int kbeg,
    const float* __restrict__ Bw, int ldb, int m0, int n0,
    float (*__restrict__ As)[64][36], float (*__restrict__ Bs)[64][64],
    float acc[4][4])
{
  int tid = threadIdx.x;
  int r = tid >> 2, p = tid & 3;
  const float* arow = A + (size_t)(m0 + r) * lda + kbeg;
#pragma unroll
  for (int i = 0; i < 8; ++i) {
    int idx = tid + 128 * i;
    int k = idx >> 4, c = (idx & 15) << 2;
    *(float4*)&Bs[0][k][c] = *(const float4*)(Bw + (size_t)k * ldb + n0 + c);
  }
#pragma unroll
  for (int j = 0; j < 4; ++j) {
    int kl = p * 16 + j * 4;
    float4 vv = *(const float4*)(arow + kl);
    As[0][kl + 0][r] = vv.x; As[0][kl + 1][r] = vv.y;
    As[0][kl + 2][r] = vv.z; As[0][kl + 3][r] = vv.w;
  }
  __syncthreads();
  for (int c = 0; c < 4; ++c) {
    int cur = c & 1;
    float4 breg[8]; float4 areg[4];
    if (c < 3) {
      int kb = (c + 1) * 64;
#pragma unroll
      for (int i = 0; i < 8; ++i) {
        int idx = tid + 128 * i;
        int k = idx >> 4, cc = (idx & 15) << 2;
        breg[i] = *(const float4*)(Bw + (size_t)(kb + k) * ldb + n0 + cc);
      }
#pragma unroll
      for (int j = 0; j < 4; ++j) areg[j] = *(const float4*)(arow + kb + p * 16 + j * 4);
    }
    gemm_chunk(As[cur], Bs[cur], acc);
    if (c < 3) {
      int nxt = cur ^ 1;
#pragma unroll
      for (int i = 0; i < 8; ++i) {
        int idx = tid + 128 * i;
        int k = idx >> 4, cc = (idx & 15) << 2;
        *(float4*)&Bs[nxt][k][cc] = breg[i];
      }
#pragma unroll
      for (int j = 0; j < 4; ++j) {
        int kl = p * 16 + j * 4;
        As[nxt][kl + 0][r] = areg[j].x; As[nxt][kl + 1][r] = areg[j].y;
        As[nxt][kl + 2][r] = areg[j].z; As[nxt][kl + 3][r] = areg[j].w;
      }
      __syncthreads();
    }
  }
}

// ---------- QKV + layer-1 K/V hoist: grid (4,16,5) x 128 ----------
// z=0: Q0  z=1: K0  z=2: V0  z=3: K1  z=4: V1 (K/V depend only on tgt)
__global__ __launch_bounds__(128) void qkv5_kernel(
    const float* __restrict__ src, const float* __restrict__ tgt,
    const float* __restrict__ ln1g, const float* __restrict__ ln1b,
    const float* __restrict__ lntg0, const float* __restrict__ lntb0,
    const float* __restrict__ lntg1, const float* __restrict__ lntb1,
    const float* __restrict__ wq,  const float* __restrict__ bq,
    const float* __restrict__ wk0, const float* __restrict__ bk0,
    const float* __restrict__ wv0, const float* __restrict__ bv0,
    const float* __restrict__ wk1, const float* __restrict__ bk1,
    const float* __restrict__ wv1, const float* __restrict__ bv1,
    float* __restrict__ Qb, float* __restrict__ Kb0, float* __restrict__ Vb0,
    float* __restrict__ Kb1, float* __restrict__ Vb1)
{
  __shared__ __align__(16) float As[2][64][36];
  __shared__ __align__(16) float Bs[2][64][64];
  int z = blockIdx.z;
  int m0 = blockIdx.y * 32, n0 = blockIdx.x * 64;
  const float* A  = (z == 0) ? src : tgt;
  const float* g  = (z == 0) ? ln1g : (z <= 2) ? lntg0 : lntg1;
  const float* bb = (z == 0) ? ln1b : (z <= 2) ? lntb0 : lntb1;
  const float* Bw = (z == 0) ? wq : (z == 1) ? wk0 : (z == 2) ? wv0 : (z == 3) ? wk1 : wv1;
  const float* bias = (z == 0) ? bq : (z == 1) ? bk0 : (z == 2) ? bv0 : (z == 3) ? bk1 : bv1;
  float* dst = (z == 0) ? Qb : (z == 1) ? Kb0 : (z == 2) ? Vb0 : (z == 3) ? Kb1 : Vb1;
  float acc[4][4] = {};
  gemm_ln(A, g, bb, Bw, DMODEL, m0, n0, As, Bs, acc);
  int tid = threadIdx.x, tx = tid & 15, ty = tid >> 4;
  int c0 = n0 + tx * 4;
  float4 bias4 = *(const float4*)(bias + c0);
  const float scale = 0.1767766952966369f;  // 1/sqrt(32)
#pragma unroll
  for (int i = 0; i < 4; ++i) {
    int m = m0 + ty * 4 + i;
    float4 r;
    r.x = acc[i][0] + bias4.x;
    r.y = acc[i][1] + bias4.y;
    r.z = acc[i][2] + bias4.z;
    r.w = acc[i][3] + bias4.w;
    if (z == 0) {
      r.x *= scale; r.y *= scale; r.z *= scale; r.w *= scale;
      *(float4*)&dst[m * DMODEL + c0] = r;
    } else {
      int b = m >> 8, t = m & 255, h = c0 >> 5, d0 = c0 & 31;
      *(float4*)&dst[(size_t)(b * NH + h) * 8192 + t * DH + d0] = r;
    }
  }
}

// ---------- layer-1 Q only: grid (4,16) x 128 ----------
__global__ __launch_bounds__(128) void q_kernel(
    const float* __restrict__ srcin,
    const float* __restrict__ ln1g, const float* __restrict__ ln1b,
    const float* __restrict__ wq, const float* __restrict__ bq,
    float* __restrict__ Qb)
{
  __shared__ __align__(16) float As[2][64][36];
  __shared__ __align__(16) float Bs[2][64][64];
  int m0 = blockIdx.y * 32, n0 = blockIdx.x * 64;
  float acc[4][4] = {};
  gemm_ln(srcin, ln1g, ln1b, wq, DMODEL, m0, n0, As, Bs, acc);
  int tid = threadIdx.x, tx = tid & 15, ty = tid >> 4;
  int c0 = n0 + tx * 4;
  float4 bias4 = *(const float4*)(bq + c0);
  const float scale = 0.1767766952966369f;
#pragma unroll
  for (int i = 0; i < 4; ++i) {
    int m = m0 + ty * 4 + i;
    float4 r;
    r.x = (acc[i][0] + bias4.x) * scale;
    r.y = (acc[i][1] + bias4.y) * scale;
    r.z = (acc[i][2] + bias4.z) * scale;
    r.w = (acc[i][3] + bias4.w) * scale;
    *(float4*)&Qb[m * DMODEL + c0] = r;
  }
}

// ---------- wo GEMM + residual; also writes out-init = mm*(X+b2) ----------
__global__ __launch_bounds__(128) void wo_kernel(
    const float* __restrict__ AO, const float* __restrict__ wo,
    const float* __restrict__ srcin, const float* __restrict__ bo,
    const float* __restrict__ b2, const int* __restrict__ smask,
    float* __restrict__ X, float* __restrict__ outb)
{
  __shared__ __align__(16) float As[2][64][36];
  __shared__ __align__(16) float Bs[2][64][64];
  int m0 = blockIdx.y * 32, n0 = blockIdx.x * 64;
  float acc[4][4] = {};
  gemm_copy(AO, DMODEL, 0, wo, DMODEL, m0, n0, As, Bs, acc);
  int tid = threadIdx.x, tx = tid & 15, ty = tid >> 4;
  int c0 = n0 + tx * 4;
  float4 bov = *(const float4*)(bo + c0);
  float4 b2v = *(const float4*)(b2 + c0);
#pragma unroll
  for (int i = 0; i < 4; ++i) {
    int m = m0 + ty * 4 + i;
    float4 sv = *(const float4*)(srcin + (size_t)m * DMODEL + c0);
    float4 r;
    r.x = sv.x + bov.x + acc[i][0];
    r.y = sv.y + bov.y + acc[i][1];
    r.z = sv.z + bov.z + acc[i][2];
    r.w = sv.w + bov.w + acc[i][3];
    *(float4*)&X[(size_t)m * DMODEL + c0] = r;
    float mm = (smask[m] != 0) ? 0.0f : 1.0f;
    float4 o;
    o.x = mm * (r.x + b2v.x); o.y = mm * (r.y + b2v.y);
    o.z = mm * (r.z + b2v.z); o.w = mm * (r.w + b2v.w);
    *(float4*)&outb[(size_t)m * DMODEL + c0] = o;
  }
}

// ---------- fused FF: LN2 -> H1 tile -> ReLU -> @w2 slice -> atomic out ----------
// grid (16,16): x = 64-wide k-slice of H1 / row-slice of w2, y = 32-row group.
__global__ __launch_bounds__(128) void ff_fused_kernel(
    const float* __restrict__ X, const float* __restrict__ ln2g, const float* __restrict__ ln2b,
    const float* __restrict__ w1, const float* __restrict__ b1,
    const float* __restrict__ w2, const int* __restrict__ smask,
    float* __restrict__ outb)
{
  __shared__ __align__(16) float As[2][64][36];
  __shared__ __align__(16) float Bs[2][64][64];
  __shared__ __align__(16) float H1t[64][36];   // [k][m]
  int m0 = blockIdx.y * 32;
  int ks = blockIdx.x * 64;                     // H1 col slice / w2 row slice
  float acc[4][4] = {};
  gemm_ln(X, ln2g, ln2b, w1, 1024, m0, ks, As, Bs, acc);
  int tid = threadIdx.x, tx = tid & 15, ty = tid >> 4;
  float4 b1v = *(const float4*)(b1 + ks + tx * 4);
  // ReLU + transpose into LDS (per-thread exclusive region)
#pragma unroll
  for (int i = 0; i < 4; ++i) {
    H1t[tx * 4 + 0][ty * 4 + i] = fmaxf(acc[i][0] + b1v.x, 0.0f);
    H1t[tx * 4 + 1][ty * 4 + i] = fmaxf(acc[i][1] + b1v.y, 0.0f);
    H1t[tx * 4 + 2][ty * 4 + i] = fmaxf(acc[i][2] + b1v.z, 0.0f);
    H1t[tx * 4 + 3][ty * 4 + i] = fmaxf(acc[i][3] + b1v.w, 0.0f);
  }
  // stage first w2 chunk (Bs[0] is safe: all threads passed the c==2 sync)
  const float* w2s = w2 + (size_t)ks * DMODEL;  // rows ks..ks+63, ld = 256
#pragma unroll
  for (int i = 0; i < 8; ++i) {
    int idx = tid + 128 * i;
    int k = idx >> 4, c = (idx & 15) << 2;
    *(float4*)&Bs[0][k][c] = *(const float4*)(w2s + (size_t)k * DMODEL + c);
  }
  __syncthreads();
  int msk[4];
#pragma unroll
  for (int i = 0; i < 4; ++i) msk[i] = smask[m0 + ty * 4 + i];
  for (int nc = 0; nc < 4; ++nc) {
    int cur = nc & 1;
    float4 breg[8];
    if (nc < 3) {
      int nb = (nc + 1) * 64;
#pragma unroll
      for (int i = 0; i < 8; ++i) {
        int idx = tid + 128 * i;
        int k = idx >> 4, c = (idx & 15) << 2;
        breg[i] = *(const float4*)(w2s + (size_t)k * DMODEL + nb + c);
      }
    }
    float a2[4][4] = {};
    gemm_chunk(H1t, Bs[cur], a2);
    int c0 = nc * 64 + tx * 4;
#pragma unroll
    for (int i = 0; i < 4; ++i) {
      int m = m0 + ty * 4 + i;
      if (msk[i] == 0) {
        atomicAdd(&outb[(size_t)m * DMODEL + c0 + 0], a2[i][0]);
        atomicAdd(&outb[(size_t)m * DMODEL + c0 + 1], a2[i][1]);
        atomicAdd(&outb[(size_t)m * DMODEL + c0 + 2], a2[i][2]);
        atomicAdd(&outb[(size_t)m * DMODEL + c0 + 3], a2[i][3]);
      }
    }
    if (nc < 3) {
      int nxt = cur ^ 1;
#pragma unroll
      for (int i = 0; i < 8; ++i) {
        int idx = tid + 128 * i;
        int k = idx >> 4, c = (idx & 15) << 2;
        *(float4*)&Bs[nxt][k][c] = breg[i];
      }
      __syncthreads();
    }
  }
}

// ---------- attention: unchanged from verified version ----------
__global__ __launch_bounds__(256) void attn_kernel(
    const float* __restrict__ Qb, const float* __restrict__ Kb, const float* __restrict__ Vb,
    const float* __restrict__ rpe, const int* __restrict__ tmask,
    const float* __restrict__ wrl, const float* __restrict__ brl,
    float* __restrict__ AO)
{
  __shared__ float Ks[256][32];
  __shared__ float Vt[32][260];
  __shared__ float ps[4][256];
  __shared__ float qs[16][32];
  __shared__ float wks[5][32];
  __shared__ float wvs[5][32];
  int bid = blockIdx.x;
  int b = bid >> 7, h = (bid >> 4) & 7, s0 = (bid & 15) << 4;
  int tid = threadIdx.x;
  const float* Kp = Kb + (size_t)(b * NH + h) * 8192;
  const float* Vp = Vb + (size_t)(b * NH + h) * 8192;
  {
    int t = tid;
    const float4* kr = (const float4*)(Kp + t * DH);
    const float4* vr = (const float4*)(Vp + t * DH);
    int sw = t & 7;
#pragma unroll
    for (int c = 0; c < 8; ++c) {
      float4 k4 = kr[c];
      *(float4*)&Ks[t][(c ^ sw) * 4] = k4;
    }
#pragma unroll
    for (int c = 0; c < 8; ++c) {
      float4 v4 = vr[c];
      Vt[c*4+0][t] = v4.x; Vt[c*4+1][t] = v4.y; Vt[c*4+2][t] = v4.z; Vt[c*4+3][t] = v4.w;
    }
  }
  if (tid < 160) {
    int j = tid >> 5, d = tid & 31;
    wks[j][d] = (j < 4) ? wrl[j * 512 + h * DH + d]       : brl[h * DH + d];
    wvs[j][d] = (j < 4) ? wrl[j * 512 + 256 + h * DH + d] : brl[256 + h * DH + d];
  }
  if (tid >= 128) {
    int u = tid - 128;
    int rr = u >> 3, cc = u & 7;
    *(float4*)&qs[rr][cc*4] =
        *(const float4*)&Qb[(b * 256 + s0 + rr) * DMODEL + h * DH + cc * 4];
  }
  __syncthreads();

  int w = tid >> 6, lane = tid & 63;
  int msk[4];
#pragma unroll
  for (int it = 0; it < 4; ++it) msk[it] = tmask[b * 256 + it * 64 + lane];

  for (int i = 0; i < 4; ++i) {
    int sl = w * 4 + i;
    int s = s0 + sl;
    float4 q4[8];
#pragma unroll
    for (int c = 0; c < 8; ++c) q4[c] = *(const float4*)&qs[sl][c * 4];
    float qw[4]; float qbr = 0.0f;
#pragma unroll
    for (int j = 0; j < 4; ++j) {
      float t0 = 0;
#pragma unroll
      for (int c = 0; c < 8; ++c) {
        float4 wv4 = *(const float4*)&wks[j][c * 4];
        t0 += q4[c].x*wv4.x + q4[c].y*wv4.y + q4[c].z*wv4.z + q4[c].w*wv4.w;
      }
      qw[j] = t0;
    }
#pragma unroll
    for (int c = 0; c < 8; ++c) {
      float4 wv4 = *(const float4*)&wks[4][c * 4];
      qbr += q4[c].x*wv4.x + q4[c].y*wv4.y + q4[c].z*wv4.z + q4[c].w*wv4.w;
    }
    const float4* rp4 = (const float4*)(rpe + (size_t)(b * 256 + s) * 1024);
    float sc[4]; float4 rr[4];
#pragma unroll
    for (int it = 0; it < 4; ++it) {
      int t = it * 64 + lane;
      int sw = t & 7;
      float sv = 0;
#pragma unroll
      for (int c = 0; c < 8; ++c) {
        float4 k4 = *(const float4*)&Ks[t][(c ^ sw) * 4];
        sv = fmaf(q4[c].x, k4.x, sv); sv = fmaf(q4[c].y, k4.y, sv);
        sv = fmaf(q4[c].z, k4.z, sv); sv = fmaf(q4[c].w, k4.w, sv);
      }
      float4 rv = rp4[t];
      rr[it] = rv;
      sv += rv.x*qw[0] + rv.y*qw[1] + rv.z*qw[2] + rv.w*qw[3] + qbr;
      if (msk[it] != 0) sv = NEG_INF;
      sc[it] = sv;
    }
    float mval = fmaxf(fmaxf(sc[0], sc[1]), fmaxf(sc[2], sc[3]));
#pragma unroll
    for (int off = 32; off >= 1; off >>= 1) mval = fmaxf(mval, __shfl_xor(mval, off));
    float p[4], lsum = 0;
#pragma unroll
    for (int it = 0; it < 4; ++it) { p[it] = __expf(sc[it] - mval); lsum += p[it]; }
    float wj0 = 0, wj1 = 0, wj2 = 0, wj3 = 0;
#pragma unroll
    for (int it = 0; it < 4; ++it) {
      wj0 = fmaf(p[it], rr[it].x, wj0);
      wj1 = fmaf(p[it], rr[it].y, wj1);
      wj2 = fmaf(p[it], rr[it].z, wj2);
      wj3 = fmaf(p[it], rr[it].w, wj3);
    }
#pragma unroll
    for (int off = 32; off >= 1; off >>= 1) {
      lsum += __shfl_xor(lsum, off);
      wj0 += __shfl_xor(wj0, off);
      wj1 += __shfl_xor(wj1, off);
      wj2 += __shfl_xor(wj2, off);
      wj3 += __shfl_xor(wj3, off);
    }
#pragma unroll
    for (int it = 0; it < 4; ++it) ps[w][it * 64 + lane] = p[it];
    int g = lane >> 5, d = lane & 31;
    float o = 0;
#pragma unroll
    for (int n = 0; n < 32; ++n) {
      int t = g * 128 + n * 4;
      float4 p4 = *(const float4*)&ps[w][t];
      float4 v4 = *(const float4*)&Vt[d][t];
      o += p4.x*v4.x + p4.y*v4.y + p4.z*v4.z + p4.w*v4.w;
    }
    o += __shfl_xor(o, 32);
    float corr = wj0 * wvs[0][d] + wj1 * wvs[1][d] + wj2 * wvs[2][d] + wj3 * wvs[3][d];
    float oval = (o + corr) / lsum + wvs[4][d];
    if (lane < 32) AO[(b * 256 + s) * DMODEL + h * DH + d] = oval;
  }
}

extern "C" void kernel_launch(void* const* d_in, const int* in_sizes, int n_in,
                              void* d_out, int out_size, void* d_ws, size_t ws_size,
                              hipStream_t stream)
{
  const float* src  = (const float*)d_in[0];
  const float* tgt  = (const float*)d_in[1];
  const float* rpe  = (const float*)d_in[2];
  const int*   smask = (const int*)d_in[3];
  const int*   tmask = (const int*)d_in[4];
  const float* ln1g = (const float*)d_in[5];
  const float* ln1b = (const float*)d_in[6];
  const float* lntg = (const float*)d_in[7];
  const float* lntb = (const float*)d_in[8];
  const float* ln2g = (const float*)d_in[9];
  const float* ln2b = (const float*)d_in[10];
  const float* wq = (const float*)d_in[11];
  const float* bq = (const float*)d_in[12];
  const float* wk = (const float*)d_in[13];
  const float* bk = (const float*)d_in[14];
  const float* wv = (const float*)d_in[15];
  const float* bv = (const float*)d_in[16];
  const float* wo = (const float*)d_in[17];
  const float* bo = (const float*)d_in[18];
  const float* wr = (const float*)d_in[19];
  const float* br = (const float*)d_in[20];
  const float* w1 = (const float*)d_in[21];
  const float* b1 = (const float*)d_in[22];
  const float* w2 = (const float*)d_in[23];
  const float* b2 = (const float*)d_in[24];

  float* w    = (float*)d_ws;
  float* Qb   = w;
  float* Kb0  = w + 131072;
  float* Vb0  = w + 262144;
  float* Kb1  = w + 393216;
  float* Vb1  = w + 524288;
  float* AO   = w + 655360;
  float* X    = w + 786432;
  float* SRC1 = w + 917504;

  // ---- dispatch 1: Q0 + K/V for BOTH layers (K/V depend only on tgt) ----
  qkv5_kernel<<<dim3(4, 16, 5), 128, 0, stream>>>(
      src, tgt, ln1g, ln1b, lntg, lntb, lntg + 256, lntb + 256,
      wq, bq, wk, bk, wv, bv, wk + 65536, bk + 256, wv + 65536, bv + 256,
      Qb, Kb0, Vb0, Kb1, Vb1);
  // ---- layer 0 ----
  attn_kernel<<<256, 256, 0, stream>>>(Qb, Kb0, Vb0, rpe, tmask, wr, br, AO);
  wo_kernel<<<dim3(4, 16), 128, 0, stream>>>(AO, wo, src, bo, b2, smask, X, SRC1);
  ff_fused_kernel<<<dim3(16, 16), 128, 0, stream>>>(X, ln2g, ln2b, w1, b1, w2,
                                                    smask, SRC1);
  // ---- layer 1 ----
  q_kernel<<<dim3(4, 16), 128, 0, stream>>>(SRC1, ln1g + 256, ln1b + 256,
                                            wq + 65536, bq + 256, Qb);
  attn_kernel<<<256, 256, 0, stream>>>(Qb, Kb1, Vb1, rpe, tmask,
                                       wr + 2048, br + 512, AO);
  wo_kernel<<<dim3(4, 16), 128, 0, stream>>>(AO, wo + 65536, SRC1, bo + 256,
                                             b2 + 256, smask, X, (float*)d_out);
  ff_fused_kernel<<<dim3(16, 16), 128, 0, stream>>>(X, ln2g + 256, ln2b + 256,
                                                    w1 + 262144, b1 + 1024,
                                                    w2 + 262144, smask, (float*)d_out);
}

// Round 8
// 267.951 us; speedup vs baseline: 1.0922x; 1.0922x over previous
//
#include <hip/hip_runtime.h>
#include <math.h>

#define DMODEL 256
#define NH 8
#define DH 32
#define NEG_INF -1e30f

// ======================================================================
// Chunked double-buffered GEMM: 128 thr, tile 32x64, K in chunks of 64.
// (verified round-6 bodies)
// ======================================================================
__device__ __forceinline__ void gemm_chunk(const float (*__restrict__ As)[36],
                                           const float (*__restrict__ Bs)[64],
                                           float acc[4][4])
{
  int tid = threadIdx.x;
  int tx = tid & 15, ty = tid >> 4;
#pragma unroll 8
  for (int k = 0; k < 64; ++k) {
    float4 a  = *(const float4*)&As[k][ty * 4];
    float4 bv = *(const float4*)&Bs[k][tx * 4];
    acc[0][0] = fmaf(a.x, bv.x, acc[0][0]); acc[0][1] = fmaf(a.x, bv.y, acc[0][1]);
    acc[0][2] = fmaf(a.x, bv.z, acc[0][2]); acc[0][3] = fmaf(a.x, bv.w, acc[0][3]);
    acc[1][0] = fmaf(a.y, bv.x, acc[1][0]); acc[1][1] = fmaf(a.y, bv.y, acc[1][1]);
    acc[1][2] = fmaf(a.y, bv.z, acc[1][2]); acc[1][3] = fmaf(a.y, bv.w, acc[1][3]);
    acc[2][0] = fmaf(a.z, bv.x, acc[2][0]); acc[2][1] = fmaf(a.z, bv.y, acc[2][1]);
    acc[2][2] = fmaf(a.z, bv.z, acc[2][2]); acc[2][3] = fmaf(a.z, bv.w, acc[2][3]);
    acc[3][0] = fmaf(a.w, bv.x, acc[3][0]); acc[3][1] = fmaf(a.w, bv.y, acc[3][1]);
    acc[3][2] = fmaf(a.w, bv.z, acc[3][2]); acc[3][3] = fmaf(a.w, bv.w, acc[3][3]);
  }
}

// A supplied by LayerNorm over a 256-wide row held in registers.
__device__ __forceinline__ void gemm_ln(
    const float* __restrict__ Xsrc,
    const float* __restrict__ g, const float* __restrict__ b,
    const float* __restrict__ Bw, int ldb, int m0, int n0,
    float (*__restrict__ As)[64][36], float (*__restrict__ Bs)[64][64],
    float acc[4][4])
{
  int tid = threadIdx.x;
  int r = tid >> 2, p = tid & 3;
  const float* row = Xsrc + (size_t)(m0 + r) * DMODEL;
  float4 v[16];
  float s = 0.f, ss = 0.f;
#pragma unroll
  for (int j = 0; j < 16; ++j) {
    int kg = (j >> 2) * 64 + p * 16 + (j & 3) * 4;
    v[j] = *(const float4*)(row + kg);
    s  += v[j].x + v[j].y + v[j].z + v[j].w;
    ss += v[j].x * v[j].x + v[j].y * v[j].y + v[j].z * v[j].z + v[j].w * v[j].w;
  }
  s  += __shfl_xor(s, 1);  s  += __shfl_xor(s, 2);
  ss += __shfl_xor(ss, 1); ss += __shfl_xor(ss, 2);
  float mean = s * (1.0f / 256.0f);
  float var  = ss * (1.0f / 256.0f) - mean * mean;
  float rstd = rsqrtf(var + 1e-5f);
#pragma unroll
  for (int j = 0; j < 16; ++j) {
    v[j].x = (v[j].x - mean) * rstd;
    v[j].y = (v[j].y - mean) * rstd;
    v[j].z = (v[j].z - mean) * rstd;
    v[j].w = (v[j].w - mean) * rstd;
  }
#pragma unroll
  for (int i = 0; i < 8; ++i) {
    int idx = tid + 128 * i;
    int k = idx >> 4, c = (idx & 15) << 2;
    *(float4*)&Bs[0][k][c] = *(const float4*)(Bw + (size_t)k * ldb + n0 + c);
  }
#pragma unroll
  for (int j = 0; j < 4; ++j) {
    int kl = p * 16 + j * 4;
    float4 gg = *(const float4*)(g + kl);
    float4 bb = *(const float4*)(b + kl);
    As[0][kl + 0][r] = v[j].x * gg.x + bb.x;
    As[0][kl + 1][r] = v[j].y * gg.y + bb.y;
    As[0][kl + 2][r] = v[j].z * gg.z + bb.z;
    As[0][kl + 3][r] = v[j].w * gg.w + bb.w;
  }
  __syncthreads();
  for (int c = 0; c < 4; ++c) {
    int cur = c & 1;
    float4 breg[8];
    if (c < 3) {
      int kb = (c + 1) * 64;
#pragma unroll
      for (int i = 0; i < 8; ++i) {
        int idx = tid + 128 * i;
        int k = idx >> 4, cc = (idx & 15) << 2;
        breg[i] = *(const float4*)(Bw + (size_t)(kb + k) * ldb + n0 + cc);
      }
    }
    gemm_chunk(As[cur], Bs[cur], acc);
    if (c < 3) {
      int nxt = cur ^ 1;
      int kb = (c + 1) * 64;
#pragma unroll
      for (int i = 0; i < 8; ++i) {
        int idx = tid + 128 * i;
        int k = idx >> 4, cc = (idx & 15) << 2;
        *(float4*)&Bs[nxt][k][cc] = breg[i];
      }
#pragma unroll
      for (int j = 0; j < 4; ++j) {
        int kl = p * 16 + j * 4;
        float4 gg = *(const float4*)(g + kb + kl);
        float4 bb = *(const float4*)(b + kb + kl);
        float4 vv = v[(c + 1) * 4 + j];
        As[nxt][kl + 0][r] = vv.x * gg.x + bb.x;
        As[nxt][kl + 1][r] = vv.y * gg.y + bb.y;
        As[nxt][kl + 2][r] = vv.z * gg.z + bb.z;
        As[nxt][kl + 3][r] = vv.w * gg.w + bb.w;
      }
      __syncthreads();
    }
  }
}

// A loaded straight from global (no LN).
__device__ __forceinline__ void gemm_copy(
    const float* __restrict__ A, int lda, int kbeg,
    const float* __restrict__ Bw, int ldb, int m0, int n0,
    float (*__restrict__ As)[64][36], float (*__restrict__ Bs)[64][64],
    float acc[4][4])
{
  int tid = threadIdx.x;
  int r = tid >> 2, p = tid & 3;
  const float* arow = A + (size_t)(m0 + r) * lda + kbeg;
#pragma unroll
  for (int i = 0; i < 8; ++i) {
    int idx = tid + 128 * i;
    int k = idx >> 4, c = (idx & 15) << 2;
    *(float4*)&Bs[0][k][c] = *(const float4*)(Bw + (size_t)k * ldb + n0 + c);
  }
#pragma unroll
  for (int j = 0; j < 4; ++j) {
    int kl = p * 16 + j * 4;
    float4 vv = *(const float4*)(arow + kl);
    As[0][kl + 0][r] = vv.x; As[0][kl + 1][r] = vv.y;
    As[0][kl + 2][r] = vv.z; As[0][kl + 3][r] = vv.w;
  }
  __syncthreads();
  for (int c = 0; c < 4; ++c) {
    int cur = c & 1;
    float4 breg[8]; float4 areg[4];
    if (c < 3) {
      int kb = (c + 1) * 64;
#pragma unroll
      for (int i = 0; i < 8; ++i) {
        int idx = tid + 128 * i;
        int k = idx >> 4, cc = (idx & 15) << 2;
        breg[i] = *(const float4*)(Bw + (size_t)(kb + k) * ldb + n0 + cc);
      }
#pragma unroll
      for (int j = 0; j < 4; ++j) areg[j] = *(const float4*)(arow + kb + p * 16 + j * 4);
    }
    gemm_chunk(As[cur], Bs[cur], acc);
    if (c < 3) {
      int nxt = cur ^ 1;
#pragma unroll
      for (int i = 0; i < 8; ++i) {
        int idx = tid + 128 * i;
        int k = idx >> 4, cc = (idx & 15) << 2;
        *(float4*)&Bs[nxt][k][cc] = breg[i];
      }
#pragma unroll
      for (int j = 0; j < 4; ++j) {
        int kl = p * 16 + j * 4;
        As[nxt][kl + 0][r] = areg[j].x; As[nxt][kl + 1][r] = areg[j].y;
        As[nxt][kl + 2][r] = areg[j].z; As[nxt][kl + 3][r] = areg[j].w;
      }
      __syncthreads();
    }
  }
}

// ---------- QKV + layer-1 K/V hoist: grid (4,16,5) x 128 ----------
// z=0: Q0  z=1: K0  z=2: V0  z=3: K1  z=4: V1 (K/V depend only on tgt)
__global__ __launch_bounds__(128) void qkv5_kernel(
    const float* __restrict__ src, const float* __restrict__ tgt,
    const float* __restrict__ ln1g, const float* __restrict__ ln1b,
    const float* __restrict__ lntg0, const float* __restrict__ lntb0,
    const float* __restrict__ lntg1, const float* __restrict__ lntb1,
    const float* __restrict__ wq,  const float* __restrict__ bq,
    const float* __restrict__ wk0, const float* __restrict__ bk0,
    const float* __restrict__ wv0, const float* __restrict__ bv0,
    const float* __restrict__ wk1, const float* __restrict__ bk1,
    const float* __restrict__ wv1, const float* __restrict__ bv1,
    float* __restrict__ Qb, float* __restrict__ Kb0, float* __restrict__ Vb0,
    float* __restrict__ Kb1, float* __restrict__ Vb1)
{
  __shared__ __align__(16) float As[2][64][36];
  __shared__ __align__(16) float Bs[2][64][64];
  int z = blockIdx.z;
  int m0 = blockIdx.y * 32, n0 = blockIdx.x * 64;
  const float* A  = (z == 0) ? src : tgt;
  const float* g  = (z == 0) ? ln1g : (z <= 2) ? lntg0 : lntg1;
  const float* bb = (z == 0) ? ln1b : (z <= 2) ? lntb0 : lntb1;
  const float* Bw = (z == 0) ? wq : (z == 1) ? wk0 : (z == 2) ? wv0 : (z == 3) ? wk1 : wv1;
  const float* bias = (z == 0) ? bq : (z == 1) ? bk0 : (z == 2) ? bv0 : (z == 3) ? bk1 : bv1;
  float* dst = (z == 0) ? Qb : (z == 1) ? Kb0 : (z == 2) ? Vb0 : (z == 3) ? Kb1 : Vb1;
  float acc[4][4] = {};
  gemm_ln(A, g, bb, Bw, DMODEL, m0, n0, As, Bs, acc);
  int tid = threadIdx.x, tx = tid & 15, ty = tid >> 4;
  int c0 = n0 + tx * 4;
  float4 bias4 = *(const float4*)(bias + c0);
  const float scale = 0.1767766952966369f;  // 1/sqrt(32)
#pragma unroll
  for (int i = 0; i < 4; ++i) {
    int m = m0 + ty * 4 + i;
    float4 r;
    r.x = acc[i][0] + bias4.x;
    r.y = acc[i][1] + bias4.y;
    r.z = acc[i][2] + bias4.z;
    r.w = acc[i][3] + bias4.w;
    if (z == 0) {
      r.x *= scale; r.y *= scale; r.z *= scale; r.w *= scale;
      *(float4*)&dst[m * DMODEL + c0] = r;
    } else {
      int b = m >> 8, t = m & 255, h = c0 >> 5, d0 = c0 & 31;
      *(float4*)&dst[(size_t)(b * NH + h) * 8192 + t * DH + d0] = r;
    }
  }
}

// ---------- layer-1 Q only: grid (4,16) x 128 ----------
__global__ __launch_bounds__(128) void q_kernel(
    const float* __restrict__ srcin,
    const float* __restrict__ ln1g, const float* __restrict__ ln1b,
    const float* __restrict__ wq, const float* __restrict__ bq,
    float* __restrict__ Qb)
{
  __shared__ __align__(16) float As[2][64][36];
  __shared__ __align__(16) float Bs[2][64][64];
  int m0 = blockIdx.y * 32, n0 = blockIdx.x * 64;
  float acc[4][4] = {};
  gemm_ln(srcin, ln1g, ln1b, wq, DMODEL, m0, n0, As, Bs, acc);
  int tid = threadIdx.x, tx = tid & 15, ty = tid >> 4;
  int c0 = n0 + tx * 4;
  float4 bias4 = *(const float4*)(bq + c0);
  const float scale = 0.1767766952966369f;
#pragma unroll
  for (int i = 0; i < 4; ++i) {
    int m = m0 + ty * 4 + i;
    float4 r;
    r.x = (acc[i][0] + bias4.x) * scale;
    r.y = (acc[i][1] + bias4.y) * scale;
    r.z = (acc[i][2] + bias4.z) * scale;
    r.w = (acc[i][3] + bias4.w) * scale;
    *(float4*)&Qb[m * DMODEL + c0] = r;
  }
}

// ---------- wo GEMM + residual; also writes out-init = mm*(X+b2) ----------
__global__ __launch_bounds__(128) void wo_kernel(
    const float* __restrict__ AO, const float* __restrict__ wo,
    const float* __restrict__ srcin, const float* __restrict__ bo,
    const float* __restrict__ b2, const int* __restrict__ smask,
    float* __restrict__ X, float* __restrict__ outb)
{
  __shared__ __align__(16) float As[2][64][36];
  __shared__ __align__(16) float Bs[2][64][64];
  int m0 = blockIdx.y * 32, n0 = blockIdx.x * 64;
  float acc[4][4] = {};
  gemm_copy(AO, DMODEL, 0, wo, DMODEL, m0, n0, As, Bs, acc);
  int tid = threadIdx.x, tx = tid & 15, ty = tid >> 4;
  int c0 = n0 + tx * 4;
  float4 bov = *(const float4*)(bo + c0);
  float4 b2v = *(const float4*)(b2 + c0);
#pragma unroll
  for (int i = 0; i < 4; ++i) {
    int m = m0 + ty * 4 + i;
    float4 sv = *(const float4*)(srcin + (size_t)m * DMODEL + c0);
    float4 r;
    r.x = sv.x + bov.x + acc[i][0];
    r.y = sv.y + bov.y + acc[i][1];
    r.z = sv.z + bov.z + acc[i][2];
    r.w = sv.w + bov.w + acc[i][3];
    *(float4*)&X[(size_t)m * DMODEL + c0] = r;
    float mm = (smask[m] != 0) ? 0.0f : 1.0f;
    float4 o;
    o.x = mm * (r.x + b2v.x); o.y = mm * (r.y + b2v.y);
    o.z = mm * (r.z + b2v.z); o.w = mm * (r.w + b2v.w);
    *(float4*)&outb[(size_t)m * DMODEL + c0] = o;
  }
}

// ---------- FF1 + fused LN2 + ReLU -> H1 : grid (16,16) ----------
__global__ __launch_bounds__(128) void ff1_kernel(
    const float* __restrict__ X, const float* __restrict__ ln2g, const float* __restrict__ ln2b,
    const float* __restrict__ w1, const float* __restrict__ b1,
    float* __restrict__ H1)
{
  __shared__ __align__(16) float As[2][64][36];
  __shared__ __align__(16) float Bs[2][64][64];
  int m0 = blockIdx.y * 32, n0 = blockIdx.x * 64;
  float acc[4][4] = {};
  gemm_ln(X, ln2g, ln2b, w1, 1024, m0, n0, As, Bs, acc);
  int tid = threadIdx.x, tx = tid & 15, ty = tid >> 4;
  int c0 = n0 + tx * 4;
  float4 b1v = *(const float4*)(b1 + c0);
#pragma unroll
  for (int i = 0; i < 4; ++i) {
    int m = m0 + ty * 4 + i;
    float4 r;
    r.x = fmaxf(acc[i][0] + b1v.x, 0.0f);
    r.y = fmaxf(acc[i][1] + b1v.y, 0.0f);
    r.z = fmaxf(acc[i][2] + b1v.z, 0.0f);
    r.w = fmaxf(acc[i][3] + b1v.w, 0.0f);
    *(float4*)&H1[(size_t)m * 1024 + c0] = r;
  }
}

// ---------- FF2 split-K=4, masked atomic accumulate : grid (4,16,4) ----------
__global__ __launch_bounds__(128) void ff2_kernel(
    const float* __restrict__ H1, const float* __restrict__ w2,
    const int* __restrict__ smask, float* __restrict__ outb)
{
  __shared__ __align__(16) float As[2][64][36];
  __shared__ __align__(16) float Bs[2][64][64];
  int m0 = blockIdx.y * 32, n0 = blockIdx.x * 64;
  int kbeg = blockIdx.z * 256;
  float acc[4][4] = {};
  gemm_copy(H1, 1024, kbeg, w2 + (size_t)kbeg * DMODEL, DMODEL, m0, n0, As, Bs, acc);
  int tid = threadIdx.x, tx = tid & 15, ty = tid >> 4;
  int c0 = n0 + tx * 4;
#pragma unroll
  for (int i = 0; i < 4; ++i) {
    int m = m0 + ty * 4 + i;
    if (smask[m] == 0) {
      atomicAdd(&outb[(size_t)m * DMODEL + c0 + 0], acc[i][0]);
      atomicAdd(&outb[(size_t)m * DMODEL + c0 + 1], acc[i][1]);
      atomicAdd(&outb[(size_t)m * DMODEL + c0 + 2], acc[i][2]);
      atomicAdd(&outb[(size_t)m * DMODEL + c0 + 3], acc[i][3]);
    }
  }
}

// ---------- attention: unchanged from verified version ----------
__global__ __launch_bounds__(256) void attn_kernel(
    const float* __restrict__ Qb, const float* __restrict__ Kb, const float* __restrict__ Vb,
    const float* __restrict__ rpe, const int* __restrict__ tmask,
    const float* __restrict__ wrl, const float* __restrict__ brl,
    float* __restrict__ AO)
{
  __shared__ float Ks[256][32];
  __shared__ float Vt[32][260];
  __shared__ float ps[4][256];
  __shared__ float qs[16][32];
  __shared__ float wks[5][32];
  __shared__ float wvs[5][32];
  int bid = blockIdx.x;
  int b = bid >> 7, h = (bid >> 4) & 7, s0 = (bid & 15) << 4;
  int tid = threadIdx.x;
  const float* Kp = Kb + (size_t)(b * NH + h) * 8192;
  const float* Vp = Vb + (size_t)(b * NH + h) * 8192;
  {
    int t = tid;
    const float4* kr = (const float4*)(Kp + t * DH);
    const float4* vr = (const float4*)(Vp + t * DH);
    int sw = t & 7;
#pragma unroll
    for (int c = 0; c < 8; ++c) {
      float4 k4 = kr[c];
      *(float4*)&Ks[t][(c ^ sw) * 4] = k4;
    }
#pragma unroll
    for (int c = 0; c < 8; ++c) {
      float4 v4 = vr[c];
      Vt[c*4+0][t] = v4.x; Vt[c*4+1][t] = v4.y; Vt[c*4+2][t] = v4.z; Vt[c*4+3][t] = v4.w;
    }
  }
  if (tid < 160) {
    int j = tid >> 5, d = tid & 31;
    wks[j][d] = (j < 4) ? wrl[j * 512 + h * DH + d]       : brl[h * DH + d];
    wvs[j][d] = (j < 4) ? wrl[j * 512 + 256 + h * DH + d] : brl[256 + h * DH + d];
  }
  if (tid >= 128) {
    int u = tid - 128;
    int rr = u >> 3, cc = u & 7;
    *(float4*)&qs[rr][cc*4] =
        *(const float4*)&Qb[(b * 256 + s0 + rr) * DMODEL + h * DH + cc * 4];
  }
  __syncthreads();

  int w = tid >> 6, lane = tid & 63;
  int msk[4];
#pragma unroll
  for (int it = 0; it < 4; ++it) msk[it] = tmask[b * 256 + it * 64 + lane];

  for (int i = 0; i < 4; ++i) {
    int sl = w * 4 + i;
    int s = s0 + sl;
    float4 q4[8];
#pragma unroll
    for (int c = 0; c < 8; ++c) q4[c] = *(const float4*)&qs[sl][c * 4];
    float qw[4]; float qbr = 0.0f;
#pragma unroll
    for (int j = 0; j < 4; ++j) {
      float t0 = 0;
#pragma unroll
      for (int c = 0; c < 8; ++c) {
        float4 wv4 = *(const float4*)&wks[j][c * 4];
        t0 += q4[c].x*wv4.x + q4[c].y*wv4.y + q4[c].z*wv4.z + q4[c].w*wv4.w;
      }
      qw[j] = t0;
    }
#pragma unroll
    for (int c = 0; c < 8; ++c) {
      float4 wv4 = *(const float4*)&wks[4][c * 4];
      qbr += q4[c].x*wv4.x + q4[c].y*wv4.y + q4[c].z*wv4.z + q4[c].w*wv4.w;
    }
    const float4* rp4 = (const float4*)(rpe + (size_t)(b * 256 + s) * 1024);
    float sc[4]; float4 rr[4];
#pragma unroll
    for (int it = 0; it < 4; ++it) {
      int t = it * 64 + lane;
      int sw = t & 7;
      float sv = 0;
#pragma unroll
      for (int c = 0; c < 8; ++c) {
        float4 k4 = *(const float4*)&Ks[t][(c ^ sw) * 4];
        sv = fmaf(q4[c].x, k4.x, sv); sv = fmaf(q4[c].y, k4.y, sv);
        sv = fmaf(q4[c].z, k4.z, sv); sv = fmaf(q4[c].w, k4.w, sv);
      }
      float4 rv = rp4[t];
      rr[it] = rv;
      sv += rv.x*qw[0] + rv.y*qw[1] + rv.z*qw[2] + rv.w*qw[3] + qbr;
      if (msk[it] != 0) sv = NEG_INF;
      sc[it] = sv;
    }
    float mval = fmaxf(fmaxf(sc[0], sc[1]), fmaxf(sc[2], sc[3]));
#pragma unroll
    for (int off = 32; off >= 1; off >>= 1) mval = fmaxf(mval, __shfl_xor(mval, off));
    float p[4], lsum = 0;
#pragma unroll
    for (int it = 0; it < 4; ++it) { p[it] = __expf(sc[it] - mval); lsum += p[it]; }
    float wj0 = 0, wj1 = 0, wj2 = 0, wj3 = 0;
#pragma unroll
    for (int it = 0; it < 4; ++it) {
      wj0 = fmaf(p[it], rr[it].x, wj0);
      wj1 = fmaf(p[it], rr[it].y, wj1);
      wj2 = fmaf(p[it], rr[it].z, wj2);
      wj3 = fmaf(p[it], rr[it].w, wj3);
    }
#pragma unroll
    for (int off = 32; off >= 1; off >>= 1) {
      lsum += __shfl_xor(lsum, off);
      wj0 += __shfl_xor(wj0, off);
      wj1 += __shfl_xor(wj1, off);
      wj2 += __shfl_xor(wj2, off);
      wj3 += __shfl_xor(wj3, off);
    }
#pragma unroll
    for (int it = 0; it < 4; ++it) ps[w][it * 64 + lane] = p[it];
    int g = lane >> 5, d = lane & 31;
    float o = 0;
#pragma unroll
    for (int n = 0; n < 32; ++n) {
      int t = g * 128 + n * 4;
      float4 p4 = *(const float4*)&ps[w][t];
      float4 v4 = *(const float4*)&Vt[d][t];
      o += p4.x*v4.x + p4.y*v4.y + p4.z*v4.z + p4.w*v4.w;
    }
    o += __shfl_xor(o, 32);
    float corr = wj0 * wvs[0][d] + wj1 * wvs[1][d] + wj2 * wvs[2][d] + wj3 * wvs[3][d];
    float oval = (o + corr) / lsum + wvs[4][d];
    if (lane < 32) AO[(b * 256 + s) * DMODEL + h * DH + d] = oval;
  }
}

extern "C" void kernel_launch(void* const* d_in, const int* in_sizes, int n_in,
                              void* d_out, int out_size, void* d_ws, size_t ws_size,
                              hipStream_t stream)
{
  const float* src  = (const float*)d_in[0];
  const float* tgt  = (const float*)d_in[1];
  const float* rpe  = (const float*)d_in[2];
  const int*   smask = (const int*)d_in[3];
  const int*   tmask = (const int*)d_in[4];
  const float* ln1g = (const float*)d_in[5];
  const float* ln1b = (const float*)d_in[6];
  const float* lntg = (const float*)d_in[7];
  const float* lntb = (const float*)d_in[8];
  const float* ln2g = (const float*)d_in[9];
  const float* ln2b = (const float*)d_in[10];
  const float* wq = (const float*)d_in[11];
  const float* bq = (const float*)d_in[12];
  const float* wk = (const float*)d_in[13];
  const float* bk = (const float*)d_in[14];
  const float* wv = (const float*)d_in[15];
  const float* bv = (const float*)d_in[16];
  const float* wo = (const float*)d_in[17];
  const float* bo = (const float*)d_in[18];
  const float* wr = (const float*)d_in[19];
  const float* br = (const float*)d_in[20];
  const float* w1 = (const float*)d_in[21];
  const float* b1 = (const float*)d_in[22];
  const float* w2 = (const float*)d_in[23];
  const float* b2 = (const float*)d_in[24];

  float* w    = (float*)d_ws;
  float* Qb   = w;
  float* Kb0  = w + 131072;
  float* Vb0  = w + 262144;
  float* Kb1  = w + 393216;
  float* Vb1  = w + 524288;
  float* AO   = w + 655360;
  float* X    = w + 786432;
  float* SRC1 = w + 917504;
  float* H1   = w + 1048576;   // 512*1024 floats

  // ---- dispatch 1: Q0 + K/V for BOTH layers (K/V depend only on tgt) ----
  qkv5_kernel<<<dim3(4, 16, 5), 128, 0, stream>>>(
      src, tgt, ln1g, ln1b, lntg, lntb, lntg + 256, lntb + 256,
      wq, bq, wk, bk, wv, bv, wk + 65536, bk + 256, wv + 65536, bv + 256,
      Qb, Kb0, Vb0, Kb1, Vb1);
  // ---- layer 0 ----
  attn_kernel<<<256, 256, 0, stream>>>(Qb, Kb0, Vb0, rpe, tmask, wr, br, AO);
  wo_kernel<<<dim3(4, 16), 128, 0, stream>>>(AO, wo, src, bo, b2, smask, X, SRC1);
  ff1_kernel<<<dim3(16, 16), 128, 0, stream>>>(X, ln2g, ln2b, w1, b1, H1);
  ff2_kernel<<<dim3(4, 16, 4), 128, 0, stream>>>(H1, w2, smask, SRC1);
  // ---- layer 1 ----
  q_kernel<<<dim3(4, 16), 128, 0, stream>>>(SRC1, ln1g + 256, ln1b + 256,
                                            wq + 65536, bq + 256, Qb);
  attn_kernel<<<256, 256, 0, stream>>>(Qb, Kb1, Vb1, rpe, tmask,
                                       wr + 2048, br + 512, AO);
  wo_kernel<<<dim3(4, 16), 128, 0, stream>>>(AO, wo + 65536, SRC1, bo + 256,
                                             b2 + 256, smask, X, (float*)d_out);
  ff1_kernel<<<dim3(16, 16), 128, 0, stream>>>(X, ln2g + 256, ln2b + 256,
                                               w1 + 262144, b1 + 1024, H1);
  ff2_kernel<<<dim3(4, 16, 4), 128, 0, stream>>>(H1, w2 + 262144, smask, (float*)d_out);
}